// Round 17
// baseline (204.097 us; speedup 1.0000x reference)
//
#include <hip/hip_runtime.h>

#define N_NODES 50000
#define N_EDGES 600000
#define D 128
#define BN_EPS 1e-5f
#define CAP 64            // padded CSR capacity (Poisson(12) max in-degree ~35)
#define NBIN 8
#define NPC 6250          // nodes per class
#define BINCAP 76000      // per-bin entry capacity (class count ~75000 +- 256)
#define NRANGE 200        // dst/src ranges for b12
#define RNODES 250        // nodes per range (divides 6250)

// ---------- ws layout (words); total 4,970,080 <= 4,970,112 proven in R15 ----------
#define O_BCNT_D   0            // int[8]
#define O_BCNT_S   8            // int[8]
#define O_SUMS8    16           // float[8*128]
#define O_SUMSQ8   1040         // float[8*128]
#define ZERO_WORDS 2064         // memset range (8.3 KB)
#define O_CNT_OUT  2064         // int[50048]  (written wholesale by b12)
#define O_CNT_IN   52112        // int[50048]  (written wholesale by b12)
#define O_ND       102160       // float[50000]
#define O_UNION    152160       // bins (912,000 w) then Xs (3,200,000 w) — bins dead before cvt
#define O_DBIN     152160       // uint[8*76000] = 608,000 w
#define O_SBIN     760160       // ushort[8*76000] = 304,000 w
#define O_XS       152160       // bf16[50000*128] = 3,200,000 w (aliases bins)
#define O_WPK      3352160      // bf16[128*128]
#define O_WRPK     3360352      // bf16[128*128]
#define O_PCSR     3368544      // ushort[50000*64] = 1,600,000 w
#define TOTAL_W    4968544

typedef __attribute__((ext_vector_type(8))) __bf16 bf16x8;
typedef __attribute__((ext_vector_type(4))) float f32x4;

static __device__ __forceinline__ unsigned short f2bf(float f) {
    unsigned u = __float_as_uint(f);
    unsigned r = (u + 0x7FFFu + ((u >> 16) & 1u)) >> 16;
    return (unsigned short)r;
}
static __device__ __forceinline__ float bf2f(unsigned short h) {
    return __uint_as_float(((unsigned)h) << 16);
}
static __device__ __forceinline__ void acc_u4(float* acc, const uint4& v) {
    acc[0] += __uint_as_float(v.x << 16);
    acc[1] += __uint_as_float(v.x & 0xFFFF0000u);
    acc[2] += __uint_as_float(v.y << 16);
    acc[3] += __uint_as_float(v.y & 0xFFFF0000u);
    acc[4] += __uint_as_float(v.z << 16);
    acc[5] += __uint_as_float(v.z & 0xFFFF0000u);
    acc[6] += __uint_as_float(v.w << 16);
    acc[7] += __uint_as_float(v.w & 0xFFFF0000u);
}
static __device__ __forceinline__ void packW_item(int i, const float* __restrict__ W,
                                                  const float* __restrict__ Wres,
                                                  unsigned short* __restrict__ Wpk,
                                                  unsigned short* __restrict__ Wrpk) {
    int l = i & 63;
    int t = (i >> 6) & 3;
    int c = i >> 8;
    int col = c * 16 + (l & 15);
    int k0 = t * 32 + (l >> 4) * 8;
    union { unsigned short us[8]; uint4 v; } u1, u2;
    #pragma unroll
    for (int j = 0; j < 8; ++j) {
        u1.us[j] = f2bf(W[(size_t)(k0 + j) * 128 + col]);
        u2.us[j] = f2bf(Wres[(size_t)(k0 + j) * 128 + col]);
    }
    ((uint4*)Wpk)[i] = u1.v;
    ((uint4*)Wrpk)[i] = u2.v;
}

// ---------------- K1a: edge binning (block-aggregated cursors) + W packing ----------------
__global__ void binA_kernel(const int* __restrict__ src, const int* __restrict__ dst,
                            int* __restrict__ bcnt_d, int* __restrict__ bcnt_s,
                            unsigned* __restrict__ dbin, unsigned short* __restrict__ sbin,
                            const float* __restrict__ W, const float* __restrict__ Wres,
                            unsigned short* __restrict__ Wpk, unsigned short* __restrict__ Wrpk) {
    __shared__ int lcnt[16];   // 0..7 dst classes, 8..15 src classes
    __shared__ int lbase[16];
    int t = threadIdx.x;
    int gtid = blockIdx.x * 256 + t;
    if (gtid < 2048) packW_item(gtid, W, Wres, Wpk, Wrpk);
    if (t < 16) lcnt[t] = 0;
    __syncthreads();
    bool act = gtid < N_EDGES / 2;
    int2 s2 = act ? ((const int2*)src)[gtid] : make_int2(0, 0);
    int2 d2 = act ? ((const int2*)dst)[gtid] : make_int2(0, 0);
    int cdx = d2.x / NPC, cdy = d2.y / NPC;
    int csx = s2.x / NPC, csy = s2.y / NPC;
    if (act) {
        atomicAdd(&lcnt[cdx], 1);
        atomicAdd(&lcnt[cdy], 1);
        atomicAdd(&lcnt[8 + csx], 1);
        atomicAdd(&lcnt[8 + csy], 1);
    }
    __syncthreads();
    if (t < 8) lbase[t] = atomicAdd(&bcnt_d[t], lcnt[t]);
    else if (t < 16) lbase[t] = atomicAdd(&bcnt_s[t - 8], lcnt[t]);
    __syncthreads();
    if (t < 16) lcnt[t] = 0;   // reuse as block-local cursor
    __syncthreads();
    if (act) {
        int p;
        p = lbase[cdx] + atomicAdd(&lcnt[cdx], 1);
        if (p < BINCAP) dbin[(size_t)cdx * BINCAP + p] = ((unsigned)s2.x << 16) | (unsigned)d2.x;
        p = lbase[cdy] + atomicAdd(&lcnt[cdy], 1);
        if (p < BINCAP) dbin[(size_t)cdy * BINCAP + p] = ((unsigned)s2.y << 16) | (unsigned)d2.y;
        p = lbase[8 + csx] + atomicAdd(&lcnt[8 + csx], 1);
        if (p < BINCAP) sbin[(size_t)csx * BINCAP + p] = (unsigned short)s2.x;
        p = lbase[8 + csy] + atomicAdd(&lcnt[8 + csy], 1);
        if (p < BINCAP) sbin[(size_t)csy * BINCAP + p] = (unsigned short)s2.y;
    }
}

// ---------------- K1b: LDS-staged pcsr deposit (blocks 0..199) + cnt_out count (200..399) ----------------
__global__ void b12_kernel(const int* __restrict__ bcnt_d, const int* __restrict__ bcnt_s,
                           const unsigned* __restrict__ dbin, const unsigned short* __restrict__ sbin,
                           unsigned short* __restrict__ pcsr, int* __restrict__ cnt_in,
                           int* __restrict__ cnt_out) {
    extern __shared__ char ldsraw[];
    int bid = blockIdx.x;
    int t = threadIdx.x;
    if (bid < NRANGE) {
        // deposit role: own dst nodes [lo, lo+250)
        unsigned short* lP = (unsigned short*)ldsraw;            // 250*64 ushorts = 32000B
        int* lC = (int*)(ldsraw + RNODES * CAP * 2);             // 250 ints
        for (int k = t; k < RNODES; k += 256) lC[k] = 0;
        __syncthreads();
        int lo = bid * RNODES;
        int cls = bid / (NRANGE / NBIN);
        int n = min(bcnt_d[cls], BINCAP);
        const unsigned* bin = dbin + (size_t)cls * BINCAP;
        for (int k = t; k < n; k += 256) {
            unsigned e = bin[k];
            int rel = (int)(e & 0xFFFFu) - lo;
            if ((unsigned)rel < (unsigned)RNODES) {
                int p = atomicAdd(&lC[rel], 1);
                if (p < CAP) lP[rel * CAP + p] = (unsigned short)(e >> 16);
            }
        }
        __syncthreads();
        uint4* gp = (uint4*)(pcsr + (size_t)lo * CAP);
        const uint4* sp = (const uint4*)lP;
        for (int k = t; k < RNODES * CAP / 8; k += 256) gp[k] = sp[k];
        for (int k = t; k < RNODES; k += 256) cnt_in[lo + k] = lC[k];
    } else {
        // count role: own src nodes [lo, lo+250)
        int r2 = bid - NRANGE;
        int* lC = (int*)ldsraw;
        for (int k = t; k < RNODES; k += 256) lC[k] = 0;
        __syncthreads();
        int lo = r2 * RNODES;
        int cls = r2 / (NRANGE / NBIN);
        int n = min(bcnt_s[cls], BINCAP);
        const unsigned short* bin = sbin + (size_t)cls * BINCAP;
        for (int k = t; k < n; k += 256) {
            int rel = (int)bin[k] - lo;
            if ((unsigned)rel < (unsigned)RNODES) atomicAdd(&lC[rel], 1);
        }
        __syncthreads();
        for (int k = t; k < RNODES; k += 256) cnt_out[lo + k] = lC[k];
    }
}

// ---------------- K2: Xs = X * rsqrt(deg_out) (bf16), nd = rsqrt(deg_in) ----------------
__global__ void cvt_nd_kernel(const float* __restrict__ X, const int* __restrict__ cnt_out,
                              const int* __restrict__ cnt_in, unsigned short* __restrict__ Xs,
                              float* __restrict__ nd) {
    int tid = blockIdx.x * 256 + threadIdx.x;
    if (tid >= N_NODES * 16) return;
    int row = tid >> 4;
    int sub = tid & 15;
    if (sub == 0) nd[row] = rsqrtf((float)max(cnt_in[row], 1));
    float wv = rsqrtf((float)max(cnt_out[row], 1));
    const float4* xp = (const float4*)(X + (size_t)row * 128 + sub * 8);
    float4 a = xp[0];
    float4 b = xp[1];
    union { unsigned short us[8]; uint4 u; } o;
    o.us[0] = f2bf(a.x * wv); o.us[1] = f2bf(a.y * wv);
    o.us[2] = f2bf(a.z * wv); o.us[3] = f2bf(a.w * wv);
    o.us[4] = f2bf(b.x * wv); o.us[5] = f2bf(b.y * wv);
    o.us[6] = f2bf(b.z * wv); o.us[7] = f2bf(b.w * wv);
    *(uint4*)(Xs + (size_t)row * 128 + sub * 8) = o.u;
}

// ---------------- K3: fused gather + dual MFMA GEMM + relu/residual + BN partials ----------------
__global__ __launch_bounds__(256) void fused_kernel(
    const unsigned short* __restrict__ Xs, const int* __restrict__ cnt_out,
    const int* __restrict__ cnt_in, const unsigned short* __restrict__ pcsr,
    const float* __restrict__ nd,
    const unsigned short* __restrict__ Wpk, const unsigned short* __restrict__ Wrpk,
    float* __restrict__ out, float* __restrict__ sums8, float* __restrict__ sumsq8) {
    __shared__ unsigned short P[16 * 136];
    __shared__ float lsum[128];
    __shared__ float lsq[128];
    int t = threadIdx.x;
    int w = t >> 6;
    int l = t & 63;
    int sub = l & 15;
    int g = l >> 4;
    int rt = blockIdx.x;

    int node = rt * 16 + w * 4 + g;
    const unsigned short* row = pcsr + (size_t)node * CAP;
    int cnt = min(cnt_in[node], CAP);
    float acc[8];
    #pragma unroll
    for (int j = 0; j < 8; ++j) acc[j] = 0.f;
    int e = 0;
    for (; e + 7 < cnt; e += 8) {
        int s0 = row[e], s1 = row[e + 1], s2 = row[e + 2], s3 = row[e + 3];
        int s4 = row[e + 4], s5 = row[e + 5], s6 = row[e + 6], s7 = row[e + 7];
        uint4 v0 = *(const uint4*)(Xs + (size_t)s0 * 128 + sub * 8);
        uint4 v1 = *(const uint4*)(Xs + (size_t)s1 * 128 + sub * 8);
        uint4 v2 = *(const uint4*)(Xs + (size_t)s2 * 128 + sub * 8);
        uint4 v3 = *(const uint4*)(Xs + (size_t)s3 * 128 + sub * 8);
        uint4 v4 = *(const uint4*)(Xs + (size_t)s4 * 128 + sub * 8);
        uint4 v5 = *(const uint4*)(Xs + (size_t)s5 * 128 + sub * 8);
        uint4 v6 = *(const uint4*)(Xs + (size_t)s6 * 128 + sub * 8);
        uint4 v7 = *(const uint4*)(Xs + (size_t)s7 * 128 + sub * 8);
        acc_u4(acc, v0); acc_u4(acc, v1); acc_u4(acc, v2); acc_u4(acc, v3);
        acc_u4(acc, v4); acc_u4(acc, v5); acc_u4(acc, v6); acc_u4(acc, v7);
    }
    for (; e + 3 < cnt; e += 4) {
        int s0 = row[e], s1 = row[e + 1], s2 = row[e + 2], s3 = row[e + 3];
        uint4 v0 = *(const uint4*)(Xs + (size_t)s0 * 128 + sub * 8);
        uint4 v1 = *(const uint4*)(Xs + (size_t)s1 * 128 + sub * 8);
        uint4 v2 = *(const uint4*)(Xs + (size_t)s2 * 128 + sub * 8);
        uint4 v3 = *(const uint4*)(Xs + (size_t)s3 * 128 + sub * 8);
        acc_u4(acc, v0); acc_u4(acc, v1); acc_u4(acc, v2); acc_u4(acc, v3);
    }
    for (; e < cnt; ++e) {
        int s0 = row[e];
        uint4 v0 = *(const uint4*)(Xs + (size_t)s0 * 128 + sub * 8);
        acc_u4(acc, v0);
    }
    {
        union { unsigned short us[8]; uint4 u; } o;
        #pragma unroll
        for (int j = 0; j < 8; ++j) o.us[j] = f2bf(acc[j]);
        *(uint4*)(&P[(w * 4 + g) * 136 + sub * 8]) = o.u;
    }
    __syncthreads();

    int kg = l >> 4;
    int lr = l & 15;
    int arow = rt * 16 + lr;
    float ndv = nd[arow];
    float nsinv = sqrtf((float)max(cnt_out[arow], 1));
    bf16x8 a1[4], a2[4];
    #pragma unroll
    for (int kt = 0; kt < 4; ++kt) {
        union { unsigned short us[8]; uint4 v; bf16x8 b; } v0, x0, o1, o2;
        v0.v = *(const uint4*)(&P[lr * 136 + kt * 32 + kg * 8]);
        x0.v = *(const uint4*)(Xs + (size_t)arow * 128 + kt * 32 + kg * 8);
        #pragma unroll
        for (int j = 0; j < 8; ++j) {
            o1.us[j] = f2bf(bf2f(v0.us[j]) * ndv);
            o2.us[j] = f2bf(bf2f(x0.us[j]) * nsinv);
        }
        a1[kt] = o1.b;
        a2[kt] = o2.b;
    }
    const bf16x8* BW = (const bf16x8*)Wpk;
    const bf16x8* BR = (const bf16x8*)Wrpk;

    #pragma unroll
    for (int ci = 0; ci < 2; ++ci) {
        int c = w * 2 + ci;
        f32x4 acc1 = {0.f, 0.f, 0.f, 0.f};
        f32x4 acc2 = {0.f, 0.f, 0.f, 0.f};
        #pragma unroll
        for (int kt = 0; kt < 4; ++kt)
            acc1 = __builtin_amdgcn_mfma_f32_16x16x32_bf16(a1[kt], BW[(c * 4 + kt) * 64 + l], acc1, 0, 0, 0);
        #pragma unroll
        for (int kt = 0; kt < 4; ++kt)
            acc2 = __builtin_amdgcn_mfma_f32_16x16x32_bf16(a2[kt], BR[(c * 4 + kt) * 64 + l], acc2, 0, 0, 0);
        int col = c * 16 + lr;
        float s = 0.f, s2 = 0.f;
        #pragma unroll
        for (int i = 0; i < 4; ++i) {
            int crow = rt * 16 + kg * 4 + i;  // C/D: col=lane&15, row=(lane>>4)*4+i
            float v = fmaxf(acc1[i], 0.f) + fmaxf(acc2[i], 0.f);
            out[(size_t)crow * 128 + col] = v;
            s += v;
            s2 += v * v;
        }
        s += __shfl_xor(s, 16);
        s2 += __shfl_xor(s2, 16);
        s += __shfl_xor(s, 32);
        s2 += __shfl_xor(s2, 32);
        if (l < 16) {
            lsum[col] = s;
            lsq[col] = s2;
        }
    }
    __syncthreads();
    if (t < 128) {
        int slot = (rt & 7) * 128 + t;
        atomicAdd(&sums8[slot], lsum[t]);
        atomicAdd(&sumsq8[slot], lsq[t]);
    }
}

// ---------------- K4: BatchNorm apply ----------------
__global__ void bn_apply_kernel(float* __restrict__ out, const float* __restrict__ sums8,
                                const float* __restrict__ sumsq8, const float* __restrict__ gamma,
                                const float* __restrict__ beta) {
    __shared__ float lmean[128], linv[128], lg[128], lb[128];
    int t = threadIdx.x;
    if (t < 128) {
        float s = 0.f, s2 = 0.f;
        #pragma unroll
        for (int k = 0; k < 8; ++k) {
            s += sums8[k * 128 + t];
            s2 += sumsq8[k * 128 + t];
        }
        const float invN = 1.0f / (float)N_NODES;
        float m = s * invN;
        lmean[t] = m;
        linv[t] = rsqrtf(s2 * invN - m * m + BN_EPS);
        lg[t] = gamma[t];
        lb[t] = beta[t];
    }
    __syncthreads();
    int tid = blockIdx.x * 256 + t;
    if (tid >= N_NODES * D / 4) return;
    int d0 = (tid * 4) & 127;
    float4 v = ((float4*)out)[tid];
    v.x = lg[d0] * (v.x - lmean[d0]) * linv[d0] + lb[d0];
    v.y = lg[d0 + 1] * (v.y - lmean[d0 + 1]) * linv[d0 + 1] + lb[d0 + 1];
    v.z = lg[d0 + 2] * (v.z - lmean[d0 + 2]) * linv[d0 + 2] + lb[d0 + 2];
    v.w = lg[d0 + 3] * (v.w - lmean[d0 + 3]) * linv[d0 + 3] + lb[d0 + 3];
    ((float4*)out)[tid] = v;
}

extern "C" void kernel_launch(void* const* d_in, const int* in_sizes, int n_in,
                              void* d_out, int out_size, void* d_ws, size_t ws_size,
                              hipStream_t stream) {
    const float* X = (const float*)d_in[0];
    const float* W = (const float*)d_in[1];
    const float* Wres = (const float*)d_in[2];
    const float* gamma = (const float*)d_in[3];
    const float* beta = (const float*)d_in[4];
    const int* src = (const int*)d_in[5];
    const int* dst = (const int*)d_in[6];
    float* out = (float*)d_out;
    int* wsI = (int*)d_ws;

    int* bcnt_d = wsI + O_BCNT_D;
    int* bcnt_s = wsI + O_BCNT_S;
    float* sums8 = (float*)(wsI + O_SUMS8);
    float* sumsq8 = (float*)(wsI + O_SUMSQ8);
    int* cnt_out = wsI + O_CNT_OUT;
    int* cnt_in = wsI + O_CNT_IN;
    float* nd = (float*)(wsI + O_ND);
    unsigned* dbin = (unsigned*)(wsI + O_DBIN);
    unsigned short* sbin = (unsigned short*)(wsI + O_SBIN);
    unsigned short* Xs = (unsigned short*)(wsI + O_XS);
    unsigned short* Wpk = (unsigned short*)(wsI + O_WPK);
    unsigned short* Wrpk = (unsigned short*)(wsI + O_WRPK);
    unsigned short* pcsr = (unsigned short*)(wsI + O_PCSR);

    hipMemsetAsync(d_ws, 0, (size_t)ZERO_WORDS * 4, stream);
    binA_kernel<<<(N_EDGES / 2 + 255) / 256, 256, 0, stream>>>(src, dst, bcnt_d, bcnt_s,
                                                               dbin, sbin, W, Wres, Wpk, Wrpk);
    b12_kernel<<<2 * NRANGE, 256, RNODES * CAP * 2 + RNODES * 4, stream>>>(
        bcnt_d, bcnt_s, dbin, sbin, pcsr, cnt_in, cnt_out);
    cvt_nd_kernel<<<(N_NODES * 16 + 255) / 256, 256, 0, stream>>>(X, cnt_out, cnt_in, Xs, nd);
    fused_kernel<<<N_NODES / 16, 256, 0, stream>>>(Xs, cnt_out, cnt_in, pcsr, nd,
                                                   Wpk, Wrpk, out, sums8, sumsq8);
    bn_apply_kernel<<<(N_NODES * D / 4 + 255) / 256, 256, 0, stream>>>(out, sums8, sumsq8,
                                                                       gamma, beta);
}

// Round 18
// 126.857 us; speedup vs baseline: 1.6089x; 1.6089x over previous
//
#include <hip/hip_runtime.h>

#define N_NODES 50000
#define N_EDGES 600000
#define D 128
#define BN_EPS 1e-5f
#define CAP 64            // padded CSR capacity (max in-degree ~35 for Poisson(12))
#define NBIN 8
#define NPC 6250          // nodes per class
#define BINCAP 76000      // level-1 per-class capacity
#define NRANGE 200        // level-2 range count (250 nodes each)
#define RNODES 250
#define BINCAP2 3520      // level-2 per-range capacity (mean 3000, sigma ~55)
#define NCHUNK 32         // binB blocks per class

// ---------- ws layout (words); total 4,968,944 <= 4,970,112 proven ----------
#define O_BCNT_D   0            // int[8]
#define O_BCNT_S   8            // int[8]
#define O_RCNT_D   16           // int[200]
#define O_RCNT_S   216          // int[200]
#define O_SUMS8    416          // float[8*128]
#define O_SUMSQ8   1440         // float[8*128]
#define ZERO_WORDS 2464         // memset range (9.9 KB)
#define O_CNT_OUT  2464         // int[50048] (written wholesale by b12)
#define O_CNT_IN   52512        // int[50048]
#define O_ND       102560       // float[50000]
#define O_DBIN     152560      // uint[8*76000] = 608000 w
#define O_SBIN     760560      // ushort[8*76000] = 304000 w
#define O_DBIN2    1064560     // uint[200*3520] = 704000 w
#define O_SBIN2    1768560     // ushort[200*3520] = 352000 w
#define O_XS       152560      // bf16[50000*128] = 3200000 w (aliases all bins; bins dead before cvt)
#define O_WPK      3352560     // bf16[128*128]
#define O_WRPK     3360752     // bf16[128*128]
#define O_PCSR     3368944     // ushort[50000*64] = 1600000 w

typedef __attribute__((ext_vector_type(8))) __bf16 bf16x8;
typedef __attribute__((ext_vector_type(4))) float f32x4;

static __device__ __forceinline__ unsigned short f2bf(float f) {
    unsigned u = __float_as_uint(f);
    unsigned r = (u + 0x7FFFu + ((u >> 16) & 1u)) >> 16;
    return (unsigned short)r;
}
static __device__ __forceinline__ float bf2f(unsigned short h) {
    return __uint_as_float(((unsigned)h) << 16);
}
static __device__ __forceinline__ void acc_u4(float* acc, const uint4& v) {
    acc[0] += __uint_as_float(v.x << 16);
    acc[1] += __uint_as_float(v.x & 0xFFFF0000u);
    acc[2] += __uint_as_float(v.y << 16);
    acc[3] += __uint_as_float(v.y & 0xFFFF0000u);
    acc[4] += __uint_as_float(v.z << 16);
    acc[5] += __uint_as_float(v.z & 0xFFFF0000u);
    acc[6] += __uint_as_float(v.w << 16);
    acc[7] += __uint_as_float(v.w & 0xFFFF0000u);
}
static __device__ __forceinline__ void packW_item(int i, const float* __restrict__ W,
                                                  const float* __restrict__ Wres,
                                                  unsigned short* __restrict__ Wpk,
                                                  unsigned short* __restrict__ Wrpk) {
    int l = i & 63;
    int t = (i >> 6) & 3;
    int c = i >> 8;
    int col = c * 16 + (l & 15);
    int k0 = t * 32 + (l >> 4) * 8;
    union { unsigned short us[8]; uint4 v; } u1, u2;
    #pragma unroll
    for (int j = 0; j < 8; ++j) {
        u1.us[j] = f2bf(W[(size_t)(k0 + j) * 128 + col]);
        u2.us[j] = f2bf(Wres[(size_t)(k0 + j) * 128 + col]);
    }
    ((uint4*)Wpk)[i] = u1.v;
    ((uint4*)Wrpk)[i] = u2.v;
}

// ---------------- K1a: level-1 binning (8 classes) + W packing ----------------
__global__ void binA_kernel(const int* __restrict__ src, const int* __restrict__ dst,
                            int* __restrict__ bcnt_d, int* __restrict__ bcnt_s,
                            unsigned* __restrict__ dbin, unsigned short* __restrict__ sbin,
                            const float* __restrict__ W, const float* __restrict__ Wres,
                            unsigned short* __restrict__ Wpk, unsigned short* __restrict__ Wrpk) {
    __shared__ int lcnt[16];
    __shared__ int lbase[16];
    int t = threadIdx.x;
    int gtid = blockIdx.x * 256 + t;
    if (gtid < 2048) packW_item(gtid, W, Wres, Wpk, Wrpk);
    if (t < 16) lcnt[t] = 0;
    __syncthreads();
    bool act = gtid < N_EDGES / 2;
    int2 s2 = act ? ((const int2*)src)[gtid] : make_int2(0, 0);
    int2 d2 = act ? ((const int2*)dst)[gtid] : make_int2(0, 0);
    int cdx = d2.x / NPC, cdy = d2.y / NPC;
    int csx = s2.x / NPC, csy = s2.y / NPC;
    if (act) {
        atomicAdd(&lcnt[cdx], 1);
        atomicAdd(&lcnt[cdy], 1);
        atomicAdd(&lcnt[8 + csx], 1);
        atomicAdd(&lcnt[8 + csy], 1);
    }
    __syncthreads();
    if (t < 8) lbase[t] = atomicAdd(&bcnt_d[t], lcnt[t]);
    else if (t < 16) lbase[t] = atomicAdd(&bcnt_s[t - 8], lcnt[t]);
    __syncthreads();
    if (t < 16) lcnt[t] = 0;
    __syncthreads();
    if (act) {
        int p;
        p = lbase[cdx] + atomicAdd(&lcnt[cdx], 1);
        if (p < BINCAP) dbin[(size_t)cdx * BINCAP + p] = ((unsigned)s2.x << 16) | (unsigned)d2.x;
        p = lbase[cdy] + atomicAdd(&lcnt[cdy], 1);
        if (p < BINCAP) dbin[(size_t)cdy * BINCAP + p] = ((unsigned)s2.y << 16) | (unsigned)d2.y;
        p = lbase[8 + csx] + atomicAdd(&lcnt[8 + csx], 1);
        if (p < BINCAP) sbin[(size_t)csx * BINCAP + p] = (unsigned short)s2.x;
        p = lbase[8 + csy] + atomicAdd(&lcnt[8 + csy], 1);
        if (p < BINCAP) sbin[(size_t)csy * BINCAP + p] = (unsigned short)s2.y;
    }
}

// ---------------- K1b: level-2 binning (class bin -> 25 range bins) ----------------
// 256 blocks: cls = bid>>5, chunk = bid&31. Each block scans 1/32 of its class bin
// (dst and src sides), block-aggregates counts, deposits to range bins.
__global__ void binB_kernel(const int* __restrict__ bcnt_d, const int* __restrict__ bcnt_s,
                            const unsigned* __restrict__ dbin, const unsigned short* __restrict__ sbin,
                            int* __restrict__ rcnt_d, int* __restrict__ rcnt_s,
                            unsigned* __restrict__ dbin2, unsigned short* __restrict__ sbin2) {
    __shared__ int lc[50];
    __shared__ int lb[50];
    int t = threadIdx.x;
    int cls = blockIdx.x >> 5;
    int chunk = blockIdx.x & (NCHUNK - 1);
    if (t < 50) lc[t] = 0;
    __syncthreads();
    int nd_ = min(bcnt_d[cls], BINCAP);
    int ns_ = min(bcnt_s[cls], BINCAP);
    int perd = (nd_ + NCHUNK - 1) / NCHUNK;
    int pers = (ns_ + NCHUNK - 1) / NCHUNK;
    int d_st = chunk * perd, d_en = min(d_st + perd, nd_);
    int s_st = chunk * pers, s_en = min(s_st + pers, ns_);
    const unsigned* dbc = dbin + (size_t)cls * BINCAP;
    const unsigned short* sbc = sbin + (size_t)cls * BINCAP;
    int lo = cls * NPC;
    // pass 1: count
    for (int k = d_st + t; k < d_en; k += 256) {
        int r = ((int)(dbc[k] & 0xFFFFu) - lo) / RNODES;
        atomicAdd(&lc[r], 1);
    }
    for (int k = s_st + t; k < s_en; k += 256) {
        int r = ((int)sbc[k] - lo) / RNODES;
        atomicAdd(&lc[25 + r], 1);
    }
    __syncthreads();
    if (t < 25) lb[t] = atomicAdd(&rcnt_d[cls * 25 + t], lc[t]);
    else if (t < 50) lb[t] = atomicAdd(&rcnt_s[cls * 25 + (t - 25)], lc[t]);
    __syncthreads();
    if (t < 50) lc[t] = 0;
    __syncthreads();
    // pass 2: deposit
    for (int k = d_st + t; k < d_en; k += 256) {
        unsigned e = dbc[k];
        int r = ((int)(e & 0xFFFFu) - lo) / RNODES;
        int p = lb[r] + atomicAdd(&lc[r], 1);
        if (p < BINCAP2) dbin2[(size_t)(cls * 25 + r) * BINCAP2 + p] = e;
    }
    for (int k = s_st + t; k < s_en; k += 256) {
        unsigned short e = sbc[k];
        int r = ((int)e - lo) / RNODES;
        int p = lb[25 + r] + atomicAdd(&lc[25 + r], 1);
        if (p < BINCAP2) sbin2[(size_t)(cls * 25 + r) * BINCAP2 + p] = e;
    }
}

// ---------------- K1c: LDS-staged pcsr deposit (blocks 0..199) / cnt_out count (200..399) ----------------
__global__ void b12_kernel(const int* __restrict__ rcnt_d, const int* __restrict__ rcnt_s,
                           const unsigned* __restrict__ dbin2, const unsigned short* __restrict__ sbin2,
                           unsigned short* __restrict__ pcsr, int* __restrict__ cnt_in,
                           int* __restrict__ cnt_out) {
    extern __shared__ char ldsraw[];
    int bid = blockIdx.x;
    int t = threadIdx.x;
    if (bid < NRANGE) {
        unsigned short* lP = (unsigned short*)ldsraw;        // 250*64 ushorts
        int* lC = (int*)(ldsraw + RNODES * CAP * 2);         // 250 ints
        for (int k = t; k < RNODES; k += 256) lC[k] = 0;
        __syncthreads();
        int lo = bid * RNODES;
        int n = min(rcnt_d[bid], BINCAP2);
        const unsigned* bin = dbin2 + (size_t)bid * BINCAP2;
        for (int k = t; k < n; k += 256) {
            unsigned e = bin[k];
            int rel = (int)(e & 0xFFFFu) - lo;
            int p = atomicAdd(&lC[rel], 1);
            if (p < CAP) lP[rel * CAP + p] = (unsigned short)(e >> 16);
        }
        __syncthreads();
        uint4* gp = (uint4*)(pcsr + (size_t)lo * CAP);
        const uint4* sp = (const uint4*)lP;
        for (int k = t; k < RNODES * CAP / 8; k += 256) gp[k] = sp[k];
        for (int k = t; k < RNODES; k += 256) cnt_in[lo + k] = lC[k];
    } else {
        int r2 = bid - NRANGE;
        int* lC = (int*)ldsraw;
        for (int k = t; k < RNODES; k += 256) lC[k] = 0;
        __syncthreads();
        int lo = r2 * RNODES;
        int n = min(rcnt_s[r2], BINCAP2);
        const unsigned short* bin = sbin2 + (size_t)r2 * BINCAP2;
        for (int k = t; k < n; k += 256) {
            int rel = (int)bin[k] - lo;
            atomicAdd(&lC[rel], 1);
        }
        __syncthreads();
        for (int k = t; k < RNODES; k += 256) cnt_out[lo + k] = lC[k];
    }
}

// ---------------- K2: Xs = X * rsqrt(deg_out) (bf16), nd = rsqrt(deg_in) ----------------
__global__ void cvt_nd_kernel(const float* __restrict__ X, const int* __restrict__ cnt_out,
                              const int* __restrict__ cnt_in, unsigned short* __restrict__ Xs,
                              float* __restrict__ nd) {
    int tid = blockIdx.x * 256 + threadIdx.x;
    if (tid >= N_NODES * 16) return;
    int row = tid >> 4;
    int sub = tid & 15;
    if (sub == 0) nd[row] = rsqrtf((float)max(cnt_in[row], 1));
    float wv = rsqrtf((float)max(cnt_out[row], 1));
    const float4* xp = (const float4*)(X + (size_t)row * 128 + sub * 8);
    float4 a = xp[0];
    float4 b = xp[1];
    union { unsigned short us[8]; uint4 u; } o;
    o.us[0] = f2bf(a.x * wv); o.us[1] = f2bf(a.y * wv);
    o.us[2] = f2bf(a.z * wv); o.us[3] = f2bf(a.w * wv);
    o.us[4] = f2bf(b.x * wv); o.us[5] = f2bf(b.y * wv);
    o.us[6] = f2bf(b.z * wv); o.us[7] = f2bf(b.w * wv);
    *(uint4*)(Xs + (size_t)row * 128 + sub * 8) = o.u;
}

// ---------------- K3: fused gather + dual MFMA GEMM + relu/residual + BN partials ----------------
__global__ __launch_bounds__(256) void fused_kernel(
    const unsigned short* __restrict__ Xs, const int* __restrict__ cnt_out,
    const int* __restrict__ cnt_in, const unsigned short* __restrict__ pcsr,
    const float* __restrict__ nd,
    const unsigned short* __restrict__ Wpk, const unsigned short* __restrict__ Wrpk,
    float* __restrict__ out, float* __restrict__ sums8, float* __restrict__ sumsq8) {
    __shared__ unsigned short P[16 * 136];
    __shared__ float lsum[128];
    __shared__ float lsq[128];
    int t = threadIdx.x;
    int w = t >> 6;
    int l = t & 63;
    int sub = l & 15;
    int g = l >> 4;
    int rt = blockIdx.x;

    int node = rt * 16 + w * 4 + g;
    const unsigned short* row = pcsr + (size_t)node * CAP;
    int cnt = min(cnt_in[node], CAP);
    float acc[8];
    #pragma unroll
    for (int j = 0; j < 8; ++j) acc[j] = 0.f;
    int e = 0;
    for (; e + 7 < cnt; e += 8) {
        int s0 = row[e], s1 = row[e + 1], s2 = row[e + 2], s3 = row[e + 3];
        int s4 = row[e + 4], s5 = row[e + 5], s6 = row[e + 6], s7 = row[e + 7];
        uint4 v0 = *(const uint4*)(Xs + (size_t)s0 * 128 + sub * 8);
        uint4 v1 = *(const uint4*)(Xs + (size_t)s1 * 128 + sub * 8);
        uint4 v2 = *(const uint4*)(Xs + (size_t)s2 * 128 + sub * 8);
        uint4 v3 = *(const uint4*)(Xs + (size_t)s3 * 128 + sub * 8);
        uint4 v4 = *(const uint4*)(Xs + (size_t)s4 * 128 + sub * 8);
        uint4 v5 = *(const uint4*)(Xs + (size_t)s5 * 128 + sub * 8);
        uint4 v6 = *(const uint4*)(Xs + (size_t)s6 * 128 + sub * 8);
        uint4 v7 = *(const uint4*)(Xs + (size_t)s7 * 128 + sub * 8);
        acc_u4(acc, v0); acc_u4(acc, v1); acc_u4(acc, v2); acc_u4(acc, v3);
        acc_u4(acc, v4); acc_u4(acc, v5); acc_u4(acc, v6); acc_u4(acc, v7);
    }
    for (; e + 3 < cnt; e += 4) {
        int s0 = row[e], s1 = row[e + 1], s2 = row[e + 2], s3 = row[e + 3];
        uint4 v0 = *(const uint4*)(Xs + (size_t)s0 * 128 + sub * 8);
        uint4 v1 = *(const uint4*)(Xs + (size_t)s1 * 128 + sub * 8);
        uint4 v2 = *(const uint4*)(Xs + (size_t)s2 * 128 + sub * 8);
        uint4 v3 = *(const uint4*)(Xs + (size_t)s3 * 128 + sub * 8);
        acc_u4(acc, v0); acc_u4(acc, v1); acc_u4(acc, v2); acc_u4(acc, v3);
    }
    for (; e < cnt; ++e) {
        int s0 = row[e];
        uint4 v0 = *(const uint4*)(Xs + (size_t)s0 * 128 + sub * 8);
        acc_u4(acc, v0);
    }
    {
        union { unsigned short us[8]; uint4 u; } o;
        #pragma unroll
        for (int j = 0; j < 8; ++j) o.us[j] = f2bf(acc[j]);
        *(uint4*)(&P[(w * 4 + g) * 136 + sub * 8]) = o.u;
    }
    __syncthreads();

    int kg = l >> 4;
    int lr = l & 15;
    int arow = rt * 16 + lr;
    float ndv = nd[arow];
    float nsinv = sqrtf((float)max(cnt_out[arow], 1));
    bf16x8 a1[4], a2[4];
    #pragma unroll
    for (int kt = 0; kt < 4; ++kt) {
        union { unsigned short us[8]; uint4 v; bf16x8 b; } v0, x0, o1, o2;
        v0.v = *(const uint4*)(&P[lr * 136 + kt * 32 + kg * 8]);
        x0.v = *(const uint4*)(Xs + (size_t)arow * 128 + kt * 32 + kg * 8);
        #pragma unroll
        for (int j = 0; j < 8; ++j) {
            o1.us[j] = f2bf(bf2f(v0.us[j]) * ndv);
            o2.us[j] = f2bf(bf2f(x0.us[j]) * nsinv);
        }
        a1[kt] = o1.b;
        a2[kt] = o2.b;
    }
    const bf16x8* BW = (const bf16x8*)Wpk;
    const bf16x8* BR = (const bf16x8*)Wrpk;

    #pragma unroll
    for (int ci = 0; ci < 2; ++ci) {
        int c = w * 2 + ci;
        f32x4 acc1 = {0.f, 0.f, 0.f, 0.f};
        f32x4 acc2 = {0.f, 0.f, 0.f, 0.f};
        #pragma unroll
        for (int kt = 0; kt < 4; ++kt)
            acc1 = __builtin_amdgcn_mfma_f32_16x16x32_bf16(a1[kt], BW[(c * 4 + kt) * 64 + l], acc1, 0, 0, 0);
        #pragma unroll
        for (int kt = 0; kt < 4; ++kt)
            acc2 = __builtin_amdgcn_mfma_f32_16x16x32_bf16(a2[kt], BR[(c * 4 + kt) * 64 + l], acc2, 0, 0, 0);
        int col = c * 16 + lr;
        float s = 0.f, s2 = 0.f;
        #pragma unroll
        for (int i = 0; i < 4; ++i) {
            int crow = rt * 16 + kg * 4 + i;  // C/D: col=lane&15, row=(lane>>4)*4+i
            float v = fmaxf(acc1[i], 0.f) + fmaxf(acc2[i], 0.f);
            out[(size_t)crow * 128 + col] = v;
            s += v;
            s2 += v * v;
        }
        s += __shfl_xor(s, 16);
        s2 += __shfl_xor(s2, 16);
        s += __shfl_xor(s, 32);
        s2 += __shfl_xor(s2, 32);
        if (l < 16) {
            lsum[col] = s;
            lsq[col] = s2;
        }
    }
    __syncthreads();
    if (t < 128) {
        int slot = (rt & 7) * 128 + t;
        atomicAdd(&sums8[slot], lsum[t]);
        atomicAdd(&sumsq8[slot], lsq[t]);
    }
}

// ---------------- K4: BatchNorm apply ----------------
__global__ void bn_apply_kernel(float* __restrict__ out, const float* __restrict__ sums8,
                                const float* __restrict__ sumsq8, const float* __restrict__ gamma,
                                const float* __restrict__ beta) {
    __shared__ float lmean[128], linv[128], lg[128], lb[128];
    int t = threadIdx.x;
    if (t < 128) {
        float s = 0.f, s2 = 0.f;
        #pragma unroll
        for (int k = 0; k < 8; ++k) {
            s += sums8[k * 128 + t];
            s2 += sumsq8[k * 128 + t];
        }
        const float invN = 1.0f / (float)N_NODES;
        float m = s * invN;
        lmean[t] = m;
        linv[t] = rsqrtf(s2 * invN - m * m + BN_EPS);
        lg[t] = gamma[t];
        lb[t] = beta[t];
    }
    __syncthreads();
    int tid = blockIdx.x * 256 + t;
    if (tid >= N_NODES * D / 4) return;
    int d0 = (tid * 4) & 127;
    float4 v = ((float4*)out)[tid];
    v.x = lg[d0] * (v.x - lmean[d0]) * linv[d0] + lb[d0];
    v.y = lg[d0 + 1] * (v.y - lmean[d0 + 1]) * linv[d0 + 1] + lb[d0 + 1];
    v.z = lg[d0 + 2] * (v.z - lmean[d0 + 2]) * linv[d0 + 2] + lb[d0 + 2];
    v.w = lg[d0 + 3] * (v.w - lmean[d0 + 3]) * linv[d0 + 3] + lb[d0 + 3];
    ((float4*)out)[tid] = v;
}

extern "C" void kernel_launch(void* const* d_in, const int* in_sizes, int n_in,
                              void* d_out, int out_size, void* d_ws, size_t ws_size,
                              hipStream_t stream) {
    const float* X = (const float*)d_in[0];
    const float* W = (const float*)d_in[1];
    const float* Wres = (const float*)d_in[2];
    const float* gamma = (const float*)d_in[3];
    const float* beta = (const float*)d_in[4];
    const int* src = (const int*)d_in[5];
    const int* dst = (const int*)d_in[6];
    float* out = (float*)d_out;
    int* wsI = (int*)d_ws;

    int* bcnt_d = wsI + O_BCNT_D;
    int* bcnt_s = wsI + O_BCNT_S;
    int* rcnt_d = wsI + O_RCNT_D;
    int* rcnt_s = wsI + O_RCNT_S;
    float* sums8 = (float*)(wsI + O_SUMS8);
    float* sumsq8 = (float*)(wsI + O_SUMSQ8);
    int* cnt_out = wsI + O_CNT_OUT;
    int* cnt_in = wsI + O_CNT_IN;
    float* nd = (float*)(wsI + O_ND);
    unsigned* dbin = (unsigned*)(wsI + O_DBIN);
    unsigned short* sbin = (unsigned short*)(wsI + O_SBIN);
    unsigned* dbin2 = (unsigned*)(wsI + O_DBIN2);
    unsigned short* sbin2 = (unsigned short*)(wsI + O_SBIN2);
    unsigned short* Xs = (unsigned short*)(wsI + O_XS);
    unsigned short* Wpk = (unsigned short*)(wsI + O_WPK);
    unsigned short* Wrpk = (unsigned short*)(wsI + O_WRPK);
    unsigned short* pcsr = (unsigned short*)(wsI + O_PCSR);

    hipMemsetAsync(d_ws, 0, (size_t)ZERO_WORDS * 4, stream);
    binA_kernel<<<(N_EDGES / 2 + 255) / 256, 256, 0, stream>>>(src, dst, bcnt_d, bcnt_s,
                                                               dbin, sbin, W, Wres, Wpk, Wrpk);
    binB_kernel<<<NBIN * NCHUNK, 256, 0, stream>>>(bcnt_d, bcnt_s, dbin, sbin,
                                                   rcnt_d, rcnt_s, dbin2, sbin2);
    b12_kernel<<<2 * NRANGE, 256, RNODES * CAP * 2 + RNODES * 4, stream>>>(
        rcnt_d, rcnt_s, dbin2, sbin2, pcsr, cnt_in, cnt_out);
    cvt_nd_kernel<<<(N_NODES * 16 + 255) / 256, 256, 0, stream>>>(X, cnt_out, cnt_in, Xs, nd);
    fused_kernel<<<N_NODES / 16, 256, 0, stream>>>(Xs, cnt_out, cnt_in, pcsr, nd,
                                                   Wpk, Wrpk, out, sums8, sumsq8);
    bn_apply_kernel<<<(N_NODES * D / 4 + 255) / 256, 256, 0, stream>>>(out, sums8, sumsq8,
                                                                       gamma, beta);
}